// Round 9
// baseline (3873.235 us; speedup 1.0000x reference)
//
#include <hip/hip_runtime.h>
#include <hip/hip_bf16.h>
#include <math.h>

#define Bn 128
#define Sn 128
#define Tn 8
#define En 300
#define EnP 320
#define Hn 512
#define Gn 2048
#define C2n 1024
#define NCONV 50

typedef unsigned short ushort_t;
typedef __attribute__((ext_vector_type(8))) short bf16x8;
typedef __attribute__((ext_vector_type(4))) float f32x4;
typedef __attribute__((ext_vector_type(8))) unsigned short ushort8_t;

// ---------------- workspace layout (float-unit offsets, ~78.5 MB) ----------------
#define OFF_V      0L          // bf16 128*128*1024 = 16,777,216 ush
#define OFF_E      8388608L    // bf16 1,048,576 ush
#define OFF_F2     8912896L    // bf16 1,048,576 ush
#define OFF_FC1WB  9437184L    // bf16 1024*2048
#define OFF_CWT    10485760L   // f32 50*3*1024
#define OFF_STATE  10639360L   // f32 524288: L1{hA,hB bf16[2][128][512], c f32} + L2 same
#define OFF_SYNC   11163648L   // 256 f (uint counters: [0]=layer1, [32]=layer2)
#define OFF_RMF1T  11163904L   // int [128][128]
#define OFF_RMB1T  11180288L   // int [128][128]
#define OFF_RM2FT  11196672L   // int [8][128]
#define OFF_RM2BT  11197696L   // int [8][128]
#define OFF_LENF   11198720L
#define OFF_LENA   11198848L
#define OFF_WPOS   11198976L   // f32 16384
#define OFF_ZPART  11215360L   // f32 128*50*4
#define OFF_UNION  11240960L   // featp/aspp/WihI/biasI (LSTM phase)  OR  mo (CPT phase)
#define OFF_FEATP  OFF_UNION                 // bf16 16384*320
#define OFF_ASPP   (OFF_UNION + 2621440L)    // bf16 1024*320
#define OFF_WIHI   (OFF_UNION + 2785280L)    // bf16 4 x 2048*320 (gate-interleaved)
#define OFF_BIASI  (OFF_UNION + 4096000L)    // f32 4 x 2048 (gate-interleaved)
#define OFF_MO     OFF_UNION                 // bf16 16,777,216 ush (after LSTMs)
#define WS_NEED_F  19629568L

__device__ __forceinline__ float sigm_(float x){ return 1.f/(1.f + __expf(-x)); }
__device__ __forceinline__ float tanh_(float x){ return 2.f/(1.f + __expf(-2.f*x)) - 1.f; }
__device__ __forceinline__ float bfu2f(ushort_t u){ return __uint_as_float(((unsigned int)u) << 16); }
__device__ __forceinline__ ushort_t f2bfu(float f){
    __hip_bfloat16 h = __float2bfloat16(f);
    return *reinterpret_cast<ushort_t*>(&h);
}
__device__ __forceinline__ void gload16(const void* g, void* l){
    __builtin_amdgcn_global_load_lds(
        (const __attribute__((address_space(1))) void*)g,
        (__attribute__((address_space(3))) void*)l, 16, 0, 0);
}

// ---------------- zero ----------------
__global__ void zero_kernel(float* __restrict__ p, long n){
    long i = (long)blockIdx.x*256 + threadIdx.x;
    if (i < n) p[i] = 0.f;
}

// ---------------- prep: lengths, [t][b] rowmaps, position weights ----------------
__global__ __launch_bounds__(128) void prep_kernel(
    const int* __restrict__ raw_text, const int* __restrict__ target,
    const int* __restrict__ span,
    int* __restrict__ lenf, int* __restrict__ lena,
    int* __restrict__ rmF1t, int* __restrict__ rmB1t,
    int* __restrict__ rm2Ft, int* __restrict__ rm2Bt,
    float* __restrict__ wpos)
{
    int b = blockIdx.x, tid = threadIdx.x;
    __shared__ int sh[128];
    sh[tid] = (raw_text[b*Sn + tid] != 0) ? 1 : 0;
    __syncthreads();
    for (int off = 64; off > 0; off >>= 1){
        if (tid < off) sh[tid] += sh[tid + off];
        __syncthreads();
    }
    __shared__ int lfs, las;
    if (tid == 0){
        lfs = sh[0]; lenf[b] = lfs;
        int c = 0;
        for (int tt = 0; tt < Tn; tt++) c += (target[b*Tn + tt] != 0) ? 1 : 0;
        las = c; lena[b] = c;
    }
    __syncthreads();
    int Lf = lfs, La = las;
    int t = tid;
    int rev = (t < Lf) ? (Lf - 1 - t) : t;
    rmF1t[t*Bn + b] = b*Sn + t;
    rmB1t[t*Bn + b] = b*Sn + rev;
    if (t < Tn){
        rm2Ft[t*Bn + b] = b*Tn + t;
        rm2Bt[t*Bn + b] = b*Tn + ((t < La) ? (La - 1 - t) : t);
    }
    float p0 = (float)span[b*2 + 0], p1 = (float)span[b*2 + 1];
    float j = (float)t;
    wpos[b*Sn + t] = (j < p1) ? (1.0f - (p1 - j)/40.0f) : (1.0f - (j - p0)/40.0f);
}

// ---------------- embedding gather -> bf16, K padded 300->320 ----------------
__global__ void embed_kernel(const int* __restrict__ ids, const float* __restrict__ embW,
                             ushort_t* __restrict__ out, long rows)
{
    long i = (long)blockIdx.x*256 + threadIdx.x;
    if (i >= rows*EnP) return;
    long r = i / EnP; int c = (int)(i - r*EnP);
    out[i] = (c < En) ? f2bfu(embW[(long)ids[r]*En + c]) : (ushort_t)0;
}

// ---------------- Wih convert: f32 [2048][300] -> bf16 gate-interleaved [jr][320] ----------------
__global__ void cvtpad_inter(const float* __restrict__ src, ushort_t* __restrict__ dst){
    long i = (long)blockIdx.x*256 + threadIdx.x;
    if (i >= (long)Gn*EnP) return;
    int jr = (int)(i / EnP), c = (int)(i - (long)jr*EnP);
    dst[i] = (c < En) ? f2bfu(src[(long)((jr&3)*Hn + (jr>>2))*En + c]) : (ushort_t)0;
}

// ---------------- bias reorder to gate-interleaved ----------------
__global__ void bias_inter(const float* __restrict__ src, float* __restrict__ dst){
    int i = blockIdx.x*256 + threadIdx.x;
    if (i >= Gn) return;
    dst[i] = src[(i&3)*Hn + (i>>2)];
}

// ---------------- f32 -> bf16 plain convert (fc1_w) ----------------
__global__ void cvtpad_kernel(const float* __restrict__ src, ushort_t* __restrict__ dst,
                              int rows, int K, int Kp)
{
    long i = (long)blockIdx.x*256 + threadIdx.x;
    if (i >= (long)rows*Kp) return;
    int r = (int)(i / Kp), c = (int)(i - (long)r*Kp);
    dst[i] = (c < K) ? f2bfu(src[(long)r*K + c]) : (ushort_t)0;
}

// ---------------- conv weight transpose [o][c][k] -> [o][k][c] f32 ----------------
__global__ void convw_kernel(const float* __restrict__ cw, float* __restrict__ cwT){
    int i = blockIdx.x*256 + threadIdx.x;
    if (i >= NCONV*3*1024) return;
    int o = i / 3072, rem = i % 3072, k = rem / 1024, c = rem % 1024;
    cwT[i] = cw[o*3072 + c*3 + k];
}

// ---------------- MFMA GEMM (verified r4-r8): C = bias + A[rowmap]·W^T ----------------
__global__ __launch_bounds__(256) void mfma_gemm(
    const ushort_t* __restrict__ A, int lda, const int* __restrict__ rowmap,
    const ushort_t* __restrict__ Wb, int ldw, const float* __restrict__ bias,
    ushort_t* __restrict__ C, int ldc, int M, int N, int K)
{
    __shared__ ushort_t As[128*32];
    __shared__ ushort_t Bs[128*32];
    int tid = threadIdx.x;
    int lane = tid & 63, wid = tid >> 6;
    int m0 = blockIdx.y * 128, n0 = blockIdx.x * 128;
    int wr = wid >> 1, wc = wid & 1;

    int ms0 = tid >> 2, ch0 = tid & 3;
    int arow0 = m0 + ms0, arow1 = m0 + ms0 + 64;
    if (rowmap){ arow0 = rowmap[arow0]; arow1 = rowmap[arow1]; }
    const ushort_t* Aptr0 = A + (long)arow0*lda;
    const ushort_t* Aptr1 = A + (long)arow1*lda;
    const ushort_t* Bptr0 = Wb + (long)(n0 + ms0)*ldw;
    const ushort_t* Bptr1 = Wb + (long)(n0 + ms0 + 64)*ldw;
    int swk = (ch0 ^ ((ms0 >> 1) & 3)) * 8;

    ushort_t* AsB0 = As + wid*512;
    ushort_t* AsB1 = As + 2048 + wid*512;
    ushort_t* BsB0 = Bs + wid*512;
    ushort_t* BsB1 = Bs + 2048 + wid*512;

    f32x4 acc[4][4];
    #pragma unroll
    for (int i = 0; i < 4; i++)
        #pragma unroll
        for (int j = 0; j < 4; j++) acc[i][j] = (f32x4){0.f, 0.f, 0.f, 0.f};

    int r = lane & 15, g = lane >> 4;
    for (int kt = 0; kt < K; kt += 32){
        gload16(Aptr0 + kt + swk, AsB0);
        gload16(Aptr1 + kt + swk, AsB1);
        gload16(Bptr0 + kt + swk, BsB0);
        gload16(Bptr1 + kt + swk, BsB1);
        __syncthreads();
        bf16x8 af[4], bw[4];
        #pragma unroll
        for (int i = 0; i < 4; i++){
            int msA = wr*64 + i*16 + r;
            af[i] = *(const bf16x8*)(As + msA*32 + ((g ^ ((msA >> 1) & 3)) * 8));
            int msB = wc*64 + i*16 + r;
            bw[i] = *(const bf16x8*)(Bs + msB*32 + ((g ^ ((msB >> 1) & 3)) * 8));
        }
        #pragma unroll
        for (int i = 0; i < 4; i++)
            #pragma unroll
            for (int j = 0; j < 4; j++)
                acc[i][j] = __builtin_amdgcn_mfma_f32_16x16x32_bf16(af[i], bw[j], acc[i][j], 0, 0, 0);
        __syncthreads();
    }
    #pragma unroll
    for (int i = 0; i < 4; i++){
        int row = m0 + wr*64 + i*16 + g*4;
        #pragma unroll
        for (int j = 0; j < 4; j++){
            int col = n0 + wc*64 + j*16 + r;
            float bv = bias ? bias[col] : 0.f;
            #pragma unroll
            for (int q = 0; q < 4; q++)
                C[(long)(row + q)*ldc + col] = f2bfu(acc[i][j][q] + bv);
        }
    }
}

// ---------------- persistent biLSTM: all P steps in one launch ----------------
// grid (32 j-slices, 2 dirs) = 64 blocks (<=256 CUs, co-resident). Whh+Wih staged
// in LDS ONCE. Per step: gates = Whh·h + Wih·x (x gathered via [t][b] rowmap, so
// bwd reversal is free) + bias, in-register nonlinearity (gate-interleaved quad),
// scatter h into out; device-scope monotonic-counter grid barrier between steps.
__global__ __launch_bounds__(256) void lstm_persist(
    const float* __restrict__ WhF, const float* __restrict__ WhB,
    const ushort_t* __restrict__ WihBase, long wihDirStride,
    const float* __restrict__ biasBase,
    const ushort_t* __restrict__ feat,
    const int* __restrict__ rmF, const int* __restrict__ rmB,
    ushort_t* __restrict__ hA, ushort_t* __restrict__ hB,
    float* __restrict__ cst, ushort_t* __restrict__ out,
    const int* __restrict__ lens, int P, int Pout,
    unsigned* __restrict__ sync_cnt)
{
    int dir = blockIdx.y;
    const float* Wh = dir ? WhB : WhF;
    const ushort_t* Wx = WihBase + (long)dir*wihDirStride;
    const float* bias = biasBase + dir*2048;
    const int* rm = dir ? rmB : rmF;
    ushort_t* hbufA = hA + dir*65536;
    ushort_t* hbufB = hB + dir*65536;
    float* cc = cst + dir*65536;
    int j0 = blockIdx.x * 16;
    int tid = threadIdx.x, lane = tid & 63, wv = tid >> 6;
    int r15 = lane & 15, kg = lane >> 4;

    __shared__ ushort_t WsH[64*512];   // 64KB Whh slice, XOR-swizzled
    __shared__ ushort_t WsX[64*EnP];   // 40KB Wih slice, XOR-swizzled

    // stage Whh slice (f32 -> bf16, gate-interleaved rows): 64 rows x 64 chunks
    #pragma unroll
    for (int it = 0; it < 16; it++){
        int id = it*256 + tid;
        int row = id >> 6, ch = id & 63;
        const float* src = Wh + (long)((row&3)*Hn + j0 + (row>>2))*Hn + ch*8;
        float4 f0 = *(const float4*)src;
        float4 f1 = *(const float4*)(src + 4);
        ushort8_t w8;
        w8[0]=f2bfu(f0.x); w8[1]=f2bfu(f0.y); w8[2]=f2bfu(f0.z); w8[3]=f2bfu(f0.w);
        w8[4]=f2bfu(f1.x); w8[5]=f2bfu(f1.y); w8[6]=f2bfu(f1.z); w8[7]=f2bfu(f1.w);
        *(ushort8_t*)(WsH + row*512 + ((ch ^ (row&7))*8)) = w8;
    }
    // stage Wih slice (bf16, already gate-interleaved): 64 rows x 40 chunks
    #pragma unroll
    for (int it = 0; it < 10; it++){
        int id = it*256 + tid;
        int row = id / 40, ch = id - row*40;
        ushort8_t w8 = *(const ushort8_t*)(Wx + (long)(j0*4 + row)*EnP + ch*8);
        *(ushort8_t*)(WsX + row*EnP + ((ch ^ (row&7))*8)) = w8;
    }
    __syncthreads();

    int bidx[2], lenv[2];
    #pragma unroll
    for (int jc = 0; jc < 2; jc++){
        bidx[jc] = wv*32 + jc*16 + r15;
        lenv[jc] = lens[bidx[jc]];
    }

    const ushort_t* hp = hbufA;
    ushort_t* hn = hbufB;
    for (int t = 0; t < P; ++t){
        int xrow[2];
        #pragma unroll
        for (int jc = 0; jc < 2; jc++) xrow[jc] = rm[t*Bn + bidx[jc]];

        f32x4 acc[4][2];
        #pragma unroll
        for (int i = 0; i < 4; i++){
            acc[i][0] = (f32x4){0.f,0.f,0.f,0.f};
            acc[i][1] = (f32x4){0.f,0.f,0.f,0.f};
        }
        // Whh·h : 16 K-tiles
        #pragma unroll
        for (int kt = 0; kt < 16; kt++){
            bf16x8 af[4], bh[2];
            #pragma unroll
            for (int i = 0; i < 4; i++){
                int row = i*16 + r15;
                af[i] = *(const bf16x8*)(WsH + row*512 + (((kt*4 + kg) ^ (row&7))*8));
            }
            #pragma unroll
            for (int jc = 0; jc < 2; jc++)
                bh[jc] = *(const bf16x8*)(hp + bidx[jc]*512 + kt*32 + kg*8);
            #pragma unroll
            for (int i = 0; i < 4; i++)
                #pragma unroll
                for (int jc = 0; jc < 2; jc++)
                    acc[i][jc] = __builtin_amdgcn_mfma_f32_16x16x32_bf16(af[i], bh[jc], acc[i][jc], 0, 0, 0);
        }
        // Wih·x : 10 K-tiles (K=320)
        #pragma unroll
        for (int kt = 0; kt < 10; kt++){
            bf16x8 ax[4], bx[2];
            #pragma unroll
            for (int i = 0; i < 4; i++){
                int row = i*16 + r15;
                ax[i] = *(const bf16x8*)(WsX + row*EnP + (((kt*4 + kg) ^ (row&7))*8));
            }
            #pragma unroll
            for (int jc = 0; jc < 2; jc++)
                bx[jc] = *(const bf16x8*)(feat + (long)xrow[jc]*EnP + kt*32 + kg*8);
            #pragma unroll
            for (int i = 0; i < 4; i++)
                #pragma unroll
                for (int jc = 0; jc < 2; jc++)
                    acc[i][jc] = __builtin_amdgcn_mfma_f32_16x16x32_bf16(ax[i], bx[jc], acc[i][jc], 0, 0, 0);
        }
        // epilogue: acc quad = {i,f,g,o} for (j, b)
        #pragma unroll
        for (int i = 0; i < 4; i++){
            int rowq = i*16 + kg*4;
            int j = j0 + (rowq >> 2);
            float4 b4 = *(const float4*)(bias + j0*4 + rowq);
            #pragma unroll
            for (int jc = 0; jc < 2; jc++){
                int b = bidx[jc], len = lenv[jc];
                float gi = acc[i][jc][0] + b4.x;
                float gf = acc[i][jc][1] + b4.y;
                float gg = acc[i][jc][2] + b4.z;
                float go = acc[i][jc][3] + b4.w;
                int ci = b*Hn + j;
                float cn = sigm_(gf)*cc[ci] + sigm_(gi)*tanh_(gg);
                cc[ci] = cn;
                float hv = sigm_(go)*tanh_(cn);
                hn[ci] = f2bfu(hv);
                int pos = dir ? ((t < len) ? (len - 1 - t) : t) : t;
                out[((long)b*Pout + pos)*C2n + dir*Hn + j] = (t < len) ? f2bfu(hv) : (ushort_t)0;
            }
        }
        // device-scope grid barrier (monotonic counter; 64 blocks co-resident)
        __threadfence();
        __syncthreads();
        if (tid == 0){
            atomicAdd(sync_cnt, 1u);
            unsigned tgt = 64u * (unsigned)(t + 1);
            while (atomicAdd(sync_cnt, 0u) < tgt) __builtin_amdgcn_s_sleep(1);
        }
        __syncthreads();
        __threadfence();
        const ushort_t* tmp = hp; hp = hn; hn = (ushort_t*)tmp;
    }
}

// ---------------- fused attention + fc1 + residual + pos-weight ----------------
__global__ __launch_bounds__(256) void attn2_kernel(
    ushort_t* __restrict__ v, const ushort_t* __restrict__ e,
    const ushort_t* __restrict__ F2, const ushort_t* __restrict__ mo,
    const float* __restrict__ fc1_b, const float* __restrict__ wpos)
{
    int s = blockIdx.x, b = blockIdx.y;
    ushort_t* vrow = v + ((long)b*Sn + s)*C2n;
    const ushort_t* eb = e + (long)b*Tn*C2n;
    const ushort_t* Fb = F2 + (long)b*Tn*C2n;
    const ushort_t* morow = mo + ((long)b*Sn + s)*C2n;
    int c0 = threadIdx.x * 4;

    ushort4 vv4 = *(const ushort4*)(vrow + c0);
    float v0 = bfu2f(vv4.x), v1 = bfu2f(vv4.y), v2 = bfu2f(vv4.z), v3 = bfu2f(vv4.w);

    float part[8];
    #pragma unroll
    for (int tt = 0; tt < 8; tt++){
        ushort4 ee = *(const ushort4*)(eb + tt*C2n + c0);
        part[tt] = v0*bfu2f(ee.x) + v1*bfu2f(ee.y) + v2*bfu2f(ee.z) + v3*bfu2f(ee.w);
    }
    __shared__ float red[8][4];
    int lane = threadIdx.x & 63, wid = threadIdx.x >> 6;
    #pragma unroll
    for (int tt = 0; tt < 8; tt++){
        float x = part[tt];
        for (int off = 32; off > 0; off >>= 1) x += __shfl_down(x, off);
        if (lane == 0) red[tt][wid] = x;
    }
    __syncthreads();
    float a[8]; float mx = -1e30f, sum = 0.f;
    #pragma unroll
    for (int tt = 0; tt < 8; tt++){
        float sv = red[tt][0] + red[tt][1] + red[tt][2] + red[tt][3];
        a[tt] = sv; mx = fmaxf(mx, sv);
    }
    #pragma unroll
    for (int tt = 0; tt < 8; tt++){ a[tt] = __expf(a[tt] - mx); sum += a[tt]; }
    float inv = 1.f / sum;
    #pragma unroll
    for (int tt = 0; tt < 8; tt++) a[tt] *= inv;

    float m0f = 0.f, m1f = 0.f, m2f = 0.f, m3f = 0.f;
    #pragma unroll
    for (int tt = 0; tt < 8; tt++){
        ushort4 ff = *(const ushort4*)(Fb + tt*C2n + c0);
        m0f += a[tt]*bfu2f(ff.x); m1f += a[tt]*bfu2f(ff.y);
        m2f += a[tt]*bfu2f(ff.z); m3f += a[tt]*bfu2f(ff.w);
    }
    ushort4 mm = *(const ushort4*)(morow + c0);
    float w = wpos[b*Sn + s];
    float o0 = (fmaxf(m0f + bfu2f(mm.x) + fc1_b[c0+0], 0.f) + v0) * w;
    float o1 = (fmaxf(m1f + bfu2f(mm.y) + fc1_b[c0+1], 0.f) + v1) * w;
    float o2 = (fmaxf(m2f + bfu2f(mm.z) + fc1_b[c0+2], 0.f) + v2) * w;
    float o3 = (fmaxf(m3f + bfu2f(mm.w) + fc1_b[c0+3], 0.f) + v3) * w;
    ushort4 outv;
    outv.x = f2bfu(o0); outv.y = f2bfu(o1); outv.z = f2bfu(o2); outv.w = f2bfu(o3);
    *(ushort4*)(vrow + c0) = outv;
}

// ---------------- conv1d: LDS-staged v tile (XOR-swizzled), all 50 o, partial max ----------------
__global__ __launch_bounds__(256) void conv2_kernel(
    const ushort_t* __restrict__ v, const float* __restrict__ cwT,
    const float* __restrict__ cb, float* __restrict__ zpart)
{
    int st = blockIdx.x, b = blockIdx.y;
    int s0 = st * 32;
    __shared__ ushort_t vs[34*1024];
    for (int i = threadIdx.x; i < 34*128; i += 256){
        int rr = i >> 7, ck = i & 127;
        int ss = s0 - 1 + rr;
        ushort8_t val = {0,0,0,0,0,0,0,0};
        if (ss >= 0 && ss < Sn) val = *(const ushort8_t*)(v + ((long)b*Sn + ss)*C2n + ck*8);
        *(ushort8_t*)(vs + rr*1024 + ((ck ^ (rr&7))*8)) = val;
    }
    __syncthreads();
    int sl = threadIdx.x & 31, ob = threadIdx.x >> 5;
    for (int o = ob; o < NCONV; o += 8){
        float acc = cb[o];
        #pragma unroll
        for (int k = 0; k < 3; k++){
            int row = sl + k;
            const ushort_t* vrow = vs + row*1024;
            int rsw = row & 7;
            const float* wrow = cwT + (o*3 + k)*1024;
            float a0 = 0.f;
            for (int c8 = 0; c8 < 128; c8++){
                ushort8_t vv = *(const ushort8_t*)(vrow + ((c8 ^ rsw)*8));
                const float* wp = wrow + c8*8;
                float4 wa = *(const float4*)(wp);
                float4 wb = *(const float4*)(wp + 4);
                a0 += bfu2f(vv[0])*wa.x + bfu2f(vv[1])*wa.y + bfu2f(vv[2])*wa.z + bfu2f(vv[3])*wa.w
                    + bfu2f(vv[4])*wb.x + bfu2f(vv[5])*wb.y + bfu2f(vv[6])*wb.z + bfu2f(vv[7])*wb.w;
            }
            acc += a0;
        }
        float rv = fmaxf(acc, 0.f);
        for (int off = 16; off > 0; off >>= 1) rv = fmaxf(rv, __shfl_down(rv, off));
        if (sl == 0) zpart[((long)b*NCONV + o)*4 + st] = rv;
    }
}

// ---------------- logits + log_softmax + NLL loss ----------------
__global__ __launch_bounds__(128) void loss_kernel(
    const float* __restrict__ zpart, const float* __restrict__ fcw,
    const float* __restrict__ fcb, const int* __restrict__ label,
    float* __restrict__ out)
{
    int b = threadIdx.x;
    float lg0 = fcb[0], lg1 = fcb[1], lg2 = fcb[2];
    for (int k = 0; k < NCONV; k++){
        const float* zp = zpart + ((long)b*NCONV + k)*4;
        float zm = fmaxf(fmaxf(zp[0], zp[1]), fmaxf(zp[2], zp[3]));
        lg0 += zm * fcw[k];
        lg1 += zm * fcw[NCONV + k];
        lg2 += zm * fcw[2*NCONV + k];
    }
    out[1 + b*3 + 0] = lg0;
    out[1 + b*3 + 1] = lg1;
    out[1 + b*3 + 2] = lg2;
    float mx = fmaxf(lg0, fmaxf(lg1, lg2));
    float sum = expf(lg0-mx) + expf(lg1-mx) + expf(lg2-mx);
    float lse = mx + logf(sum);
    int lb = label[b];
    float lp = ((lb == 0) ? lg0 : (lb == 1) ? lg1 : lg2) - lse;
    __shared__ float red[128];
    red[b] = lp; __syncthreads();
    for (int off = 64; off > 0; off >>= 1){
        if (b < off) red[b] += red[b + off];
        __syncthreads();
    }
    if (b == 0) out[0] = -red[0] / (float)Bn;
}

extern "C" void kernel_launch(void* const* d_in, const int* in_sizes, int n_in,
                              void* d_out, int out_size, void* d_ws, size_t ws_size,
                              hipStream_t stream)
{
    (void)in_sizes; (void)n_in; (void)out_size;
    if (ws_size < (size_t)WS_NEED_F * 4) return;   // clean absmax failure, not a fault
    const int* raw_text  = (const int*)d_in[0];
    const int* target    = (const int*)d_in[1];
    const int* span      = (const int*)d_in[2];
    const int* label     = (const int*)d_in[3];
    const float* embW    = (const float*)d_in[4];
    const float* l1f_Wih = (const float*)d_in[5];
    const float* l1f_Whh = (const float*)d_in[6];
    const float* l1f_b   = (const float*)d_in[7];
    const float* l1b_Wih = (const float*)d_in[8];
    const float* l1b_Whh = (const float*)d_in[9];
    const float* l1b_b   = (const float*)d_in[10];
    const float* l2f_Wih = (const float*)d_in[11];
    const float* l2f_Whh = (const float*)d_in[12];
    const float* l2f_b   = (const float*)d_in[13];
    const float* l2b_Wih = (const float*)d_in[14];
    const float* l2b_Whh = (const float*)d_in[15];
    const float* l2b_b   = (const float*)d_in[16];
    const float* conv_w  = (const float*)d_in[17];
    const float* conv_b  = (const float*)d_in[18];
    const float* fc1_w   = (const float*)d_in[19];
    const float* fc1_b   = (const float*)d_in[20];
    const float* fc_w    = (const float*)d_in[21];
    const float* fc_b    = (const float*)d_in[22];

    float* ws = (float*)d_ws;
    ushort_t* vbuf  = (ushort_t*)(ws + OFF_V);
    ushort_t* ebuf  = (ushort_t*)(ws + OFF_E);
    ushort_t* F2b   = (ushort_t*)(ws + OFF_F2);
    ushort_t* fc1wb = (ushort_t*)(ws + OFF_FC1WB);
    float*    cwT   = ws + OFF_CWT;
    float*    st    = ws + OFF_STATE;
    unsigned* sync  = (unsigned*)(ws + OFF_SYNC);
    int* rmF1t = (int*)(ws + OFF_RMF1T);
    int* rmB1t = (int*)(ws + OFF_RMB1T);
    int* rm2Ft = (int*)(ws + OFF_RM2FT);
    int* rm2Bt = (int*)(ws + OFF_RM2BT);
    int* lenf  = (int*)(ws + OFF_LENF);
    int* lena  = (int*)(ws + OFF_LENA);
    float* wpos = ws + OFF_WPOS;
    float* zpart= ws + OFF_ZPART;
    ushort_t* featp = (ushort_t*)(ws + OFF_FEATP);
    ushort_t* aspp  = (ushort_t*)(ws + OFF_ASPP);
    ushort_t* WihI  = (ushort_t*)(ws + OFF_WIHI);
    float*    biasI = ws + OFF_BIASI;
    ushort_t* mo    = (ushort_t*)(ws + OFF_MO);

    // state: per layer {hA bf16 [2][128][512], hB same, c f32 [2][128][512]}
    ushort_t* h1A = (ushort_t*)(st);
    ushort_t* h1B = (ushort_t*)(st + 65536);
    float*    c1  = st + 131072;
    float* st2 = st + 262144;
    ushort_t* h2A = (ushort_t*)(st2);
    ushort_t* h2B = (ushort_t*)(st2 + 65536);
    float*    c2  = st2 + 131072;

    zero_kernel<<<2049, 256, 0, stream>>>(st, 524288L + 256L);   // state + sync counters
    prep_kernel<<<Bn, 128, 0, stream>>>(raw_text, target, span, lenf, lena,
                                        rmF1t, rmB1t, rm2Ft, rm2Bt, wpos);
    embed_kernel<<<(Bn*Sn*EnP + 255)/256, 256, 0, stream>>>(raw_text, embW, featp, (long)Bn*Sn);
    embed_kernel<<<(Bn*Tn*EnP + 255)/256, 256, 0, stream>>>(target, embW, aspp, (long)Bn*Tn);

    const float* wih_src[4]  = {l1f_Wih, l1b_Wih, l2f_Wih, l2b_Wih};
    const float* bias_src[4] = {l1f_b,   l1b_b,   l2f_b,   l2b_b};
    for (int d = 0; d < 4; d++){
        cvtpad_inter<<<(Gn*EnP + 255)/256, 256, 0, stream>>>(wih_src[d], WihI + (long)d*655360);
        bias_inter<<<8, 256, 0, stream>>>(bias_src[d], biasI + d*2048);
    }
    cvtpad_kernel<<<(1024*2048 + 255)/256, 256, 0, stream>>>(fc1_w, fc1wb, 1024, 2048, 2048);
    convw_kernel<<<(NCONV*3072 + 255)/256, 256, 0, stream>>>(conv_w, cwT);

    // persistent biLSTM layers (64 co-resident blocks each)
    dim3 gl(32, 2);
    lstm_persist<<<gl, 256, 0, stream>>>(l1f_Whh, l1b_Whh, WihI, 655360L, biasI,
        featp, rmF1t, rmB1t, h1A, h1B, c1, vbuf, lenf, Sn, Sn, sync);
    lstm_persist<<<gl, 256, 0, stream>>>(l2f_Whh, l2b_Whh, WihI + 2L*655360, 655360L, biasI + 4096,
        aspp, rm2Ft, rm2Bt, h2A, h2B, c2, ebuf, lena, Tn, Tn, sync + 32);

    // F2 = e @ W1^T  (fc1_w cols 0..1023)
    dim3 gF(C2n/128, (Bn*Tn)/128);  // (8, 8)
    mfma_gemm<<<gF, 256, 0, stream>>>(ebuf, C2n, nullptr, fc1wb, 2048, nullptr, F2b, C2n, Bn*Tn, C2n, C2n);

    // 2 CPT iterations: mo = v @ W2^T, then fused attention/fc1/residual
    dim3 gm(C2n/128, (Bn*Sn)/128);  // (8, 128)
    for (int it = 0; it < 2; it++){
        mfma_gemm<<<gm, 256, 0, stream>>>(vbuf, C2n, nullptr, fc1wb + 1024, 2048, nullptr, mo, C2n, Bn*Sn, C2n, C2n);
        attn2_kernel<<<dim3(Sn, Bn), 256, 0, stream>>>(vbuf, ebuf, F2b, mo, fc1_b, wpos);
    }

    conv2_kernel<<<dim3(4, Bn), 256, 0, stream>>>(vbuf, cwT, conv_b, zpart);
    loss_kernel<<<1, 128, 0, stream>>>(zpart, fc_w, fc_b, label, (float*)d_out);
}

// Round 10
// 3567.323 us; speedup vs baseline: 1.0858x; 1.0858x over previous
//
#include <hip/hip_runtime.h>
#include <hip/hip_bf16.h>
#include <math.h>

#define Bn 128
#define Sn 128
#define Tn 8
#define En 300
#define EnP 320
#define Hn 512
#define Gn 2048
#define C2n 1024
#define NCONV 50

typedef unsigned short ushort_t;
typedef __attribute__((ext_vector_type(8))) short bf16x8;
typedef __attribute__((ext_vector_type(4))) float f32x4;
typedef __attribute__((ext_vector_type(8))) unsigned short ushort8_t;

// ---------------- workspace layout (float-unit offsets, ~78.6 MB) ----------------
#define OFF_V      0L          // bf16 128*128*1024
#define OFF_E      8388608L    // bf16 1,048,576 ush
#define OFF_F2     8912896L    // bf16 1,048,576 ush
#define OFF_FC1WB  9437184L    // bf16 1024*2048
#define OFF_CW3    10485760L   // bf16 128*3072 (conv weights, o-padded, [o][k*1024+c])
#define OFF_ZROW   10682368L   // bf16 1024 zeros (conv pad rows)
#define OFF_STATE  10682880L   // f32 524288
#define OFF_SYNC   11207168L   // 256 f (uint counters: [0]=layer1, [32]=layer2)
#define OFF_RMF1T  11207424L   // int [128][128]
#define OFF_RMB1T  11223808L
#define OFF_RM2FT  11240192L
#define OFF_RM2BT  11241216L
#define OFF_LENF   11242240L
#define OFF_LENA   11242368L
#define OFF_WPOS   11242496L   // f32 16384
#define OFF_ZMAX   11258880L   // f32 128*64
#define OFF_UNION  11267072L   // featp/aspp/WihI/biasI (LSTM)  OR  mo (CPT)
#define OFF_FEATP  OFF_UNION                 // bf16 16384*320
#define OFF_ASPP   (OFF_UNION + 2621440L)    // bf16 1024*320
#define OFF_WIHI   (OFF_UNION + 2785280L)    // bf16 4 x 2048*320 (gate-interleaved)
#define OFF_BIASI  (OFF_UNION + 4096000L)    // f32 4 x 2048 (gate-interleaved)
#define OFF_MO     OFF_UNION                 // bf16 16,777,216 ush (after LSTMs)
#define WS_NEED_F  19655680L

__device__ __forceinline__ float sigm_(float x){ return 1.f/(1.f + __expf(-x)); }
__device__ __forceinline__ float tanh_(float x){ return 2.f/(1.f + __expf(-2.f*x)) - 1.f; }
__device__ __forceinline__ float bfu2f(ushort_t u){ return __uint_as_float(((unsigned int)u) << 16); }
__device__ __forceinline__ ushort_t f2bfu(float f){
    __hip_bfloat16 h = __float2bfloat16(f);
    return *reinterpret_cast<ushort_t*>(&h);
}
__device__ __forceinline__ void gload16(const void* g, void* l){
    __builtin_amdgcn_global_load_lds(
        (const __attribute__((address_space(1))) void*)g,
        (__attribute__((address_space(3))) void*)l, 16, 0, 0);
}

// ---------------- zero ----------------
__global__ void zero_kernel(float* __restrict__ p, long n){
    long i = (long)blockIdx.x*256 + threadIdx.x;
    if (i < n) p[i] = 0.f;
}

// ---------------- prep: lengths, [t][b] rowmaps, position weights ----------------
__global__ __launch_bounds__(128) void prep_kernel(
    const int* __restrict__ raw_text, const int* __restrict__ target,
    const int* __restrict__ span,
    int* __restrict__ lenf, int* __restrict__ lena,
    int* __restrict__ rmF1t, int* __restrict__ rmB1t,
    int* __restrict__ rm2Ft, int* __restrict__ rm2Bt,
    float* __restrict__ wpos)
{
    int b = blockIdx.x, tid = threadIdx.x;
    __shared__ int sh[128];
    sh[tid] = (raw_text[b*Sn + tid] != 0) ? 1 : 0;
    __syncthreads();
    for (int off = 64; off > 0; off >>= 1){
        if (tid < off) sh[tid] += sh[tid + off];
        __syncthreads();
    }
    __shared__ int lfs, las;
    if (tid == 0){
        lfs = sh[0]; lenf[b] = lfs;
        int c = 0;
        for (int tt = 0; tt < Tn; tt++) c += (target[b*Tn + tt] != 0) ? 1 : 0;
        las = c; lena[b] = c;
    }
    __syncthreads();
    int Lf = lfs, La = las;
    int t = tid;
    int rev = (t < Lf) ? (Lf - 1 - t) : t;
    rmF1t[t*Bn + b] = b*Sn + t;
    rmB1t[t*Bn + b] = b*Sn + rev;
    if (t < Tn){
        rm2Ft[t*Bn + b] = b*Tn + t;
        rm2Bt[t*Bn + b] = b*Tn + ((t < La) ? (La - 1 - t) : t);
    }
    float p0 = (float)span[b*2 + 0], p1 = (float)span[b*2 + 1];
    float j = (float)t;
    wpos[b*Sn + t] = (j < p1) ? (1.0f - (p1 - j)/40.0f) : (1.0f - (j - p0)/40.0f);
}

// ---------------- embedding gather -> bf16, K padded 300->320 ----------------
__global__ void embed_kernel(const int* __restrict__ ids, const float* __restrict__ embW,
                             ushort_t* __restrict__ out, long rows)
{
    long i = (long)blockIdx.x*256 + threadIdx.x;
    if (i >= rows*EnP) return;
    long r = i / EnP; int c = (int)(i - r*EnP);
    out[i] = (c < En) ? f2bfu(embW[(long)ids[r]*En + c]) : (ushort_t)0;
}

// ---------------- Wih convert: f32 [2048][300] -> bf16 gate-interleaved [jr][320] ----------------
__global__ void cvtpad_inter(const float* __restrict__ src, ushort_t* __restrict__ dst){
    long i = (long)blockIdx.x*256 + threadIdx.x;
    if (i >= (long)Gn*EnP) return;
    int jr = (int)(i / EnP), c = (int)(i - (long)jr*EnP);
    dst[i] = (c < En) ? f2bfu(src[(long)((jr&3)*Hn + (jr>>2))*En + c]) : (ushort_t)0;
}

// ---------------- bias reorder to gate-interleaved ----------------
__global__ void bias_inter(const float* __restrict__ src, float* __restrict__ dst){
    int i = blockIdx.x*256 + threadIdx.x;
    if (i >= Gn) return;
    dst[i] = src[(i&3)*Hn + (i>>2)];
}

// ---------------- f32 -> bf16 plain convert (fc1_w) ----------------
__global__ void cvtpad_kernel(const float* __restrict__ src, ushort_t* __restrict__ dst,
                              int rows, int K, int Kp)
{
    long i = (long)blockIdx.x*256 + threadIdx.x;
    if (i >= (long)rows*Kp) return;
    int r = (int)(i / Kp), c = (int)(i - (long)r*Kp);
    dst[i] = (c < K) ? f2bfu(src[(long)r*K + c]) : (ushort_t)0;
}

// ---------------- conv weights -> bf16 [128 pad][k*1024+c] ----------------
__global__ void convw3_kernel(const float* __restrict__ cw, ushort_t* __restrict__ cw3){
    int i = blockIdx.x*256 + threadIdx.x;
    if (i >= 128*3072) return;
    int o = i / 3072, rem = i % 3072, k = rem / 1024, c = rem % 1024;
    cw3[i] = (o < NCONV) ? f2bfu(cw[o*3072 + c*3 + k]) : (ushort_t)0;
}

// ---------------- MFMA GEMM (verified r4-r8): C = bias + A[rowmap]·W^T ----------------
__global__ __launch_bounds__(256) void mfma_gemm(
    const ushort_t* __restrict__ A, int lda, const int* __restrict__ rowmap,
    const ushort_t* __restrict__ Wb, int ldw, const float* __restrict__ bias,
    ushort_t* __restrict__ C, int ldc, int M, int N, int K)
{
    __shared__ ushort_t As[128*32];
    __shared__ ushort_t Bs[128*32];
    int tid = threadIdx.x;
    int lane = tid & 63, wid = tid >> 6;
    int m0 = blockIdx.y * 128, n0 = blockIdx.x * 128;
    int wr = wid >> 1, wc = wid & 1;

    int ms0 = tid >> 2, ch0 = tid & 3;
    int arow0 = m0 + ms0, arow1 = m0 + ms0 + 64;
    if (rowmap){ arow0 = rowmap[arow0]; arow1 = rowmap[arow1]; }
    const ushort_t* Aptr0 = A + (long)arow0*lda;
    const ushort_t* Aptr1 = A + (long)arow1*lda;
    const ushort_t* Bptr0 = Wb + (long)(n0 + ms0)*ldw;
    const ushort_t* Bptr1 = Wb + (long)(n0 + ms0 + 64)*ldw;
    int swk = (ch0 ^ ((ms0 >> 1) & 3)) * 8;

    ushort_t* AsB0 = As + wid*512;
    ushort_t* AsB1 = As + 2048 + wid*512;
    ushort_t* BsB0 = Bs + wid*512;
    ushort_t* BsB1 = Bs + 2048 + wid*512;

    f32x4 acc[4][4];
    #pragma unroll
    for (int i = 0; i < 4; i++)
        #pragma unroll
        for (int j = 0; j < 4; j++) acc[i][j] = (f32x4){0.f, 0.f, 0.f, 0.f};

    int r = lane & 15, g = lane >> 4;
    for (int kt = 0; kt < K; kt += 32){
        gload16(Aptr0 + kt + swk, AsB0);
        gload16(Aptr1 + kt + swk, AsB1);
        gload16(Bptr0 + kt + swk, BsB0);
        gload16(Bptr1 + kt + swk, BsB1);
        __syncthreads();
        bf16x8 af[4], bw[4];
        #pragma unroll
        for (int i = 0; i < 4; i++){
            int msA = wr*64 + i*16 + r;
            af[i] = *(const bf16x8*)(As + msA*32 + ((g ^ ((msA >> 1) & 3)) * 8));
            int msB = wc*64 + i*16 + r;
            bw[i] = *(const bf16x8*)(Bs + msB*32 + ((g ^ ((msB >> 1) & 3)) * 8));
        }
        #pragma unroll
        for (int i = 0; i < 4; i++)
            #pragma unroll
            for (int j = 0; j < 4; j++)
                acc[i][j] = __builtin_amdgcn_mfma_f32_16x16x32_bf16(af[i], bw[j], acc[i][j], 0, 0, 0);
        __syncthreads();
    }
    #pragma unroll
    for (int i = 0; i < 4; i++){
        int row = m0 + wr*64 + i*16 + g*4;
        #pragma unroll
        for (int j = 0; j < 4; j++){
            int col = n0 + wc*64 + j*16 + r;
            float bv = bias ? bias[col] : 0.f;
            #pragma unroll
            for (int q = 0; q < 4; q++)
                C[(long)(row + q)*ldc + col] = f2bfu(acc[i][j][q] + bv);
        }
    }
}

// ---------------- persistent biLSTM (r9 structure; barrier poll fixed) ----------------
__global__ __launch_bounds__(256) void lstm_persist(
    const float* __restrict__ WhF, const float* __restrict__ WhB,
    const ushort_t* __restrict__ WihBase, long wihDirStride,
    const float* __restrict__ biasBase,
    const ushort_t* __restrict__ feat,
    const int* __restrict__ rmF, const int* __restrict__ rmB,
    ushort_t* __restrict__ hA, ushort_t* __restrict__ hB,
    float* __restrict__ cst, ushort_t* __restrict__ out,
    const int* __restrict__ lens, int P, int Pout,
    unsigned* __restrict__ sync_cnt)
{
    int dir = blockIdx.y;
    const float* Wh = dir ? WhB : WhF;
    const ushort_t* Wx = WihBase + (long)dir*wihDirStride;
    const float* bias = biasBase + dir*2048;
    const int* rm = dir ? rmB : rmF;
    ushort_t* hbufA = hA + dir*65536;
    ushort_t* hbufB = hB + dir*65536;
    float* cc = cst + dir*65536;
    int j0 = blockIdx.x * 16;
    int tid = threadIdx.x, lane = tid & 63, wv = tid >> 6;
    int r15 = lane & 15, kg = lane >> 4;

    __shared__ ushort_t WsH[64*512];   // 64KB Whh slice, XOR-swizzled
    __shared__ ushort_t WsX[64*EnP];   // 40KB Wih slice, XOR-swizzled

    #pragma unroll
    for (int it = 0; it < 16; it++){
        int id = it*256 + tid;
        int row = id >> 6, ch = id & 63;
        const float* src = Wh + (long)((row&3)*Hn + j0 + (row>>2))*Hn + ch*8;
        float4 f0 = *(const float4*)src;
        float4 f1 = *(const float4*)(src + 4);
        ushort8_t w8;
        w8[0]=f2bfu(f0.x); w8[1]=f2bfu(f0.y); w8[2]=f2bfu(f0.z); w8[3]=f2bfu(f0.w);
        w8[4]=f2bfu(f1.x); w8[5]=f2bfu(f1.y); w8[6]=f2bfu(f1.z); w8[7]=f2bfu(f1.w);
        *(ushort8_t*)(WsH + row*512 + ((ch ^ (row&7))*8)) = w8;
    }
    #pragma unroll
    for (int it = 0; it < 10; it++){
        int id = it*256 + tid;
        int row = id / 40, ch = id - row*40;
        ushort8_t w8 = *(const ushort8_t*)(Wx + (long)(j0*4 + row)*EnP + ch*8);
        *(ushort8_t*)(WsX + row*EnP + ((ch ^ (row&7))*8)) = w8;
    }
    __syncthreads();

    int bidx[2], lenv[2];
    #pragma unroll
    for (int jc = 0; jc < 2; jc++){
        bidx[jc] = wv*32 + jc*16 + r15;
        lenv[jc] = lens[bidx[jc]];
    }

    const ushort_t* hp = hbufA;
    ushort_t* hn = hbufB;
    for (int t = 0; t < P; ++t){
        int xrow[2];
        #pragma unroll
        for (int jc = 0; jc < 2; jc++) xrow[jc] = rm[t*Bn + bidx[jc]];

        f32x4 acc[4][2];
        #pragma unroll
        for (int i = 0; i < 4; i++){
            acc[i][0] = (f32x4){0.f,0.f,0.f,0.f};
            acc[i][1] = (f32x4){0.f,0.f,0.f,0.f};
        }
        #pragma unroll
        for (int kt = 0; kt < 16; kt++){
            bf16x8 af[4], bh[2];
            #pragma unroll
            for (int i = 0; i < 4; i++){
                int row = i*16 + r15;
                af[i] = *(const bf16x8*)(WsH + row*512 + (((kt*4 + kg) ^ (row&7))*8));
            }
            #pragma unroll
            for (int jc = 0; jc < 2; jc++)
                bh[jc] = *(const bf16x8*)(hp + bidx[jc]*512 + kt*32 + kg*8);
            #pragma unroll
            for (int i = 0; i < 4; i++)
                #pragma unroll
                for (int jc = 0; jc < 2; jc++)
                    acc[i][jc] = __builtin_amdgcn_mfma_f32_16x16x32_bf16(af[i], bh[jc], acc[i][jc], 0, 0, 0);
        }
        #pragma unroll
        for (int kt = 0; kt < 10; kt++){
            bf16x8 ax[4], bx[2];
            #pragma unroll
            for (int i = 0; i < 4; i++){
                int row = i*16 + r15;
                ax[i] = *(const bf16x8*)(WsX + row*EnP + (((kt*4 + kg) ^ (row&7))*8));
            }
            #pragma unroll
            for (int jc = 0; jc < 2; jc++)
                bx[jc] = *(const bf16x8*)(feat + (long)xrow[jc]*EnP + kt*32 + kg*8);
            #pragma unroll
            for (int i = 0; i < 4; i++)
                #pragma unroll
                for (int jc = 0; jc < 2; jc++)
                    acc[i][jc] = __builtin_amdgcn_mfma_f32_16x16x32_bf16(ax[i], bx[jc], acc[i][jc], 0, 0, 0);
        }
        #pragma unroll
        for (int i = 0; i < 4; i++){
            int rowq = i*16 + kg*4;
            int j = j0 + (rowq >> 2);
            float4 b4 = *(const float4*)(bias + j0*4 + rowq);
            #pragma unroll
            for (int jc = 0; jc < 2; jc++){
                int b = bidx[jc], len = lenv[jc];
                float gi = acc[i][jc][0] + b4.x;
                float gf = acc[i][jc][1] + b4.y;
                float gg = acc[i][jc][2] + b4.z;
                float go = acc[i][jc][3] + b4.w;
                int ci = b*Hn + j;
                float cn = sigm_(gf)*cc[ci] + sigm_(gi)*tanh_(gg);
                cc[ci] = cn;
                float hv = sigm_(go)*tanh_(cn);
                hn[ci] = f2bfu(hv);
                int pos = dir ? ((t < len) ? (len - 1 - t) : t) : t;
                out[((long)b*Pout + pos)*C2n + dir*Hn + j] = (t < len) ? f2bfu(hv) : (ushort_t)0;
            }
        }
        // grid barrier: RMW arrival, LOAD-poll (no RMW contention — r9's 23us/step bug)
        __threadfence();
        __syncthreads();
        if (tid == 0){
            atomicAdd(sync_cnt, 1u);
            unsigned tgt = 64u * (unsigned)(t + 1);
            while (__hip_atomic_load(sync_cnt, __ATOMIC_RELAXED, __HIP_MEMORY_SCOPE_AGENT) < tgt)
                __builtin_amdgcn_s_sleep(2);
        }
        __syncthreads();
        __threadfence();
        const ushort_t* tmp = hp; hp = hn; hn = (ushort_t*)tmp;
    }
}

// ---------------- fused attention + fc1 + residual + pos-weight ----------------
__global__ __launch_bounds__(256) void attn2_kernel(
    ushort_t* __restrict__ v, const ushort_t* __restrict__ e,
    const ushort_t* __restrict__ F2, const ushort_t* __restrict__ mo,
    const float* __restrict__ fc1_b, const float* __restrict__ wpos)
{
    int s = blockIdx.x, b = blockIdx.y;
    ushort_t* vrow = v + ((long)b*Sn + s)*C2n;
    const ushort_t* eb = e + (long)b*Tn*C2n;
    const ushort_t* Fb = F2 + (long)b*Tn*C2n;
    const ushort_t* morow = mo + ((long)b*Sn + s)*C2n;
    int c0 = threadIdx.x * 4;

    ushort4 vv4 = *(const ushort4*)(vrow + c0);
    float v0 = bfu2f(vv4.x), v1 = bfu2f(vv4.y), v2 = bfu2f(vv4.z), v3 = bfu2f(vv4.w);

    float part[8];
    #pragma unroll
    for (int tt = 0; tt < 8; tt++){
        ushort4 ee = *(const ushort4*)(eb + tt*C2n + c0);
        part[tt] = v0*bfu2f(ee.x) + v1*bfu2f(ee.y) + v2*bfu2f(ee.z) + v3*bfu2f(ee.w);
    }
    __shared__ float red[8][4];
    int lane = threadIdx.x & 63, wid = threadIdx.x >> 6;
    #pragma unroll
    for (int tt = 0; tt < 8; tt++){
        float x = part[tt];
        for (int off = 32; off > 0; off >>= 1) x += __shfl_down(x, off);
        if (lane == 0) red[tt][wid] = x;
    }
    __syncthreads();
    float a[8]; float mx = -1e30f, sum = 0.f;
    #pragma unroll
    for (int tt = 0; tt < 8; tt++){
        float sv = red[tt][0] + red[tt][1] + red[tt][2] + red[tt][3];
        a[tt] = sv; mx = fmaxf(mx, sv);
    }
    #pragma unroll
    for (int tt = 0; tt < 8; tt++){ a[tt] = __expf(a[tt] - mx); sum += a[tt]; }
    float inv = 1.f / sum;
    #pragma unroll
    for (int tt = 0; tt < 8; tt++) a[tt] *= inv;

    float m0f = 0.f, m1f = 0.f, m2f = 0.f, m3f = 0.f;
    #pragma unroll
    for (int tt = 0; tt < 8; tt++){
        ushort4 ff = *(const ushort4*)(Fb + tt*C2n + c0);
        m0f += a[tt]*bfu2f(ff.x); m1f += a[tt]*bfu2f(ff.y);
        m2f += a[tt]*bfu2f(ff.z); m3f += a[tt]*bfu2f(ff.w);
    }
    ushort4 mm = *(const ushort4*)(morow + c0);
    float w = wpos[b*Sn + s];
    float o0 = (fmaxf(m0f + bfu2f(mm.x) + fc1_b[c0+0], 0.f) + v0) * w;
    float o1 = (fmaxf(m1f + bfu2f(mm.y) + fc1_b[c0+1], 0.f) + v1) * w;
    float o2 = (fmaxf(m2f + bfu2f(mm.z) + fc1_b[c0+2], 0.f) + v2) * w;
    float o3 = (fmaxf(m3f + bfu2f(mm.w) + fc1_b[c0+3], 0.f) + v3) * w;
    ushort4 outv;
    outv.x = f2bfu(o0); outv.y = f2bfu(o1); outv.z = f2bfu(o2); outv.w = f2bfu(o3);
    *(ushort4*)(vrow + c0) = outv;
}

// ---------------- conv as MFMA GEMM: one block per batch; z[s=128][o=64], K=3072 ----------------
// A[s][k*1024+c] = v[b][s+k-1][c] (zero-row pad); B[o][k*1024+c] = conv_w[o][c][k] (o-padded).
// In-block max over s -> zmax[b][o] = relu(max_s z + cb[o]).
__global__ __launch_bounds__(256) void conv_mm(
    const ushort_t* __restrict__ v, const ushort_t* __restrict__ cw3,
    const ushort_t* __restrict__ zrow, const float* __restrict__ cb,
    float* __restrict__ zmax)
{
    int b = blockIdx.x;
    __shared__ ushort_t As[128*32];
    __shared__ ushort_t Bs[128*32];
    __shared__ float mxs[8][128];
    int tid = threadIdx.x, lane = tid & 63, wid = tid >> 6;
    int wr = wid >> 1, wc = wid & 1;
    int ms0 = tid >> 2, ch0 = tid & 3;
    int swk = (ch0 ^ ((ms0 >> 1) & 3)) * 8;
    const ushort_t* vb = v + (long)b*Sn*C2n;
    const ushort_t* Bp0 = cw3 + (long)ms0*3072;
    const ushort_t* Bp1 = cw3 + (long)(ms0 + 64)*3072;
    ushort_t* AsB0 = As + wid*512;
    ushort_t* AsB1 = As + 2048 + wid*512;
    ushort_t* BsB0 = Bs + wid*512;
    ushort_t* BsB1 = Bs + 2048 + wid*512;

    f32x4 acc[4][4];
    #pragma unroll
    for (int i = 0; i < 4; i++)
        #pragma unroll
        for (int j = 0; j < 4; j++) acc[i][j] = (f32x4){0.f, 0.f, 0.f, 0.f};

    int r = lane & 15, g = lane >> 4;
    for (int kt = 0; kt < 3072; kt += 32){
        int k = kt >> 10, c0 = kt & 1023;
        int ss0 = ms0 + k - 1, ss1 = ms0 + 64 + k - 1;
        const ushort_t* a0 = (ss0 >= 0 && ss0 < Sn) ? (vb + (long)ss0*C2n + c0) : zrow;
        const ushort_t* a1 = (ss1 >= 0 && ss1 < Sn) ? (vb + (long)ss1*C2n + c0) : zrow;
        gload16(a0 + swk, AsB0);
        gload16(a1 + swk, AsB1);
        gload16(Bp0 + kt + swk, BsB0);
        gload16(Bp1 + kt + swk, BsB1);
        __syncthreads();
        bf16x8 af[4], bw[4];
        #pragma unroll
        for (int i = 0; i < 4; i++){
            int msA = wr*64 + i*16 + r;
            af[i] = *(const bf16x8*)(As + msA*32 + ((g ^ ((msA >> 1) & 3)) * 8));
            int msB = wc*64 + i*16 + r;
            bw[i] = *(const bf16x8*)(Bs + msB*32 + ((g ^ ((msB >> 1) & 3)) * 8));
        }
        #pragma unroll
        for (int i = 0; i < 4; i++)
            #pragma unroll
            for (int j = 0; j < 4; j++)
                acc[i][j] = __builtin_amdgcn_mfma_f32_16x16x32_bf16(af[i], bw[j], acc[i][j], 0, 0, 0);
        __syncthreads();
    }
    // per-(wr,g) partial max over this lane's 16 rows, for each of its 4 cols
    #pragma unroll
    for (int j = 0; j < 4; j++){
        int col = wc*64 + j*16 + r;
        float m = -1e30f;
        #pragma unroll
        for (int i = 0; i < 4; i++)
            #pragma unroll
            for (int q = 0; q < 4; q++)
                m = fmaxf(m, acc[i][j][q]);
        mxs[wr*4 + g][col] = m;
    }
    __syncthreads();
    if (tid < 128){
        int col = tid;
        float m = mxs[0][col];
        #pragma unroll
        for (int rg = 1; rg < 8; rg++) m = fmaxf(m, mxs[rg][col]);
        if (col < 64){
            float bv = (col < NCONV) ? cb[col] : 0.f;
            zmax[b*64 + col] = fmaxf(m + bv, 0.f);
        }
    }
}

// ---------------- logits + log_softmax + NLL loss ----------------
__global__ __launch_bounds__(128) void loss_kernel(
    const float* __restrict__ zmax, const float* __restrict__ fcw,
    const float* __restrict__ fcb, const int* __restrict__ label,
    float* __restrict__ out)
{
    int b = threadIdx.x;
    float lg0 = fcb[0], lg1 = fcb[1], lg2 = fcb[2];
    for (int k = 0; k < NCONV; k++){
        float zm = zmax[b*64 + k];
        lg0 += zm * fcw[k];
        lg1 += zm * fcw[NCONV + k];
        lg2 += zm * fcw[2*NCONV + k];
    }
    out[1 + b*3 + 0] = lg0;
    out[1 + b*3 + 1] = lg1;
    out[1 + b*3 + 2] = lg2;
    float mx = fmaxf(lg0, fmaxf(lg1, lg2));
    float sum = expf(lg0-mx) + expf(lg1-mx) + expf(lg2-mx);
    float lse = mx + logf(sum);
    int lb = label[b];
    float lp = ((lb == 0) ? lg0 : (lb == 1) ? lg1 : lg2) - lse;
    __shared__ float red[128];
    red[b] = lp; __syncthreads();
    for (int off = 64; off > 0; off >>= 1){
        if (b < off) red[b] += red[b + off];
        __syncthreads();
    }
    if (b == 0) out[0] = -red[0] / (float)Bn;
}

extern "C" void kernel_launch(void* const* d_in, const int* in_sizes, int n_in,
                              void* d_out, int out_size, void* d_ws, size_t ws_size,
                              hipStream_t stream)
{
    (void)in_sizes; (void)n_in; (void)out_size;
    if (ws_size < (size_t)WS_NEED_F * 4) return;   // clean absmax failure, not a fault
    const int* raw_text  = (const int*)d_in[0];
    const int* target    = (const int*)d_in[1];
    const int* span      = (const int*)d_in[2];
    const int* label     = (const int*)d_in[3];
    const float* embW    = (const float*)d_in[4];
    const float* l1f_Wih = (const float*)d_in[5];
    const float* l1f_Whh = (const float*)d_in[6];
    const float* l1f_b   = (const float*)d_in[7];
    const float* l1b_Wih = (const float*)d_in[8];
    const float* l1b_Whh = (const float*)d_in[9];
    const float* l1b_b   = (const float*)d_in[10];
    const float* l2f_Wih = (const float*)d_in[11];
    const float* l2f_Whh = (const float*)d_in[12];
    const float* l2f_b   = (const float*)d_in[13];
    const float* l2b_Wih = (const float*)d_in[14];
    const float* l2b_Whh = (const float*)d_in[15];
    const float* l2b_b   = (const float*)d_in[16];
    const float* conv_w  = (const float*)d_in[17];
    const float* conv_b  = (const float*)d_in[18];
    const float* fc1_w   = (const float*)d_in[19];
    const float* fc1_b   = (const float*)d_in[20];
    const float* fc_w    = (const float*)d_in[21];
    const float* fc_b    = (const float*)d_in[22];

    float* ws = (float*)d_ws;
    ushort_t* vbuf  = (ushort_t*)(ws + OFF_V);
    ushort_t* ebuf  = (ushort_t*)(ws + OFF_E);
    ushort_t* F2b   = (ushort_t*)(ws + OFF_F2);
    ushort_t* fc1wb = (ushort_t*)(ws + OFF_FC1WB);
    ushort_t* cw3   = (ushort_t*)(ws + OFF_CW3);
    ushort_t* zrow  = (ushort_t*)(ws + OFF_ZROW);
    float*    st    = ws + OFF_STATE;
    unsigned* sync  = (unsigned*)(ws + OFF_SYNC);
    int* rmF1t = (int*)(ws + OFF_RMF1T);
    int* rmB1t = (int*)(ws + OFF_RMB1T);
    int* rm2Ft = (int*)(ws + OFF_RM2FT);
    int* rm2Bt = (int*)(ws + OFF_RM2BT);
    int* lenf  = (int*)(ws + OFF_LENF);
    int* lena  = (int*)(ws + OFF_LENA);
    float* wpos = ws + OFF_WPOS;
    float* zmax = ws + OFF_ZMAX;
    ushort_t* featp = (ushort_t*)(ws + OFF_FEATP);
    ushort_t* aspp  = (ushort_t*)(ws + OFF_ASPP);
    ushort_t* WihI  = (ushort_t*)(ws + OFF_WIHI);
    float*    biasI = ws + OFF_BIASI;
    ushort_t* mo    = (ushort_t*)(ws + OFF_MO);

    ushort_t* h1A = (ushort_t*)(st);
    ushort_t* h1B = (ushort_t*)(st + 65536);
    float*    c1  = st + 131072;
    float* st2 = st + 262144;
    ushort_t* h2A = (ushort_t*)(st2);
    ushort_t* h2B = (ushort_t*)(st2 + 65536);
    float*    c2  = st2 + 131072;

    // zero zrow + state + sync (contiguous span)
    zero_kernel<<<2052, 256, 0, stream>>>(ws + OFF_ZROW, 525056L);
    prep_kernel<<<Bn, 128, 0, stream>>>(raw_text, target, span, lenf, lena,
                                        rmF1t, rmB1t, rm2Ft, rm2Bt, wpos);
    embed_kernel<<<(Bn*Sn*EnP + 255)/256, 256, 0, stream>>>(raw_text, embW, featp, (long)Bn*Sn);
    embed_kernel<<<(Bn*Tn*EnP + 255)/256, 256, 0, stream>>>(target, embW, aspp, (long)Bn*Tn);

    const float* wih_src[4]  = {l1f_Wih, l1b_Wih, l2f_Wih, l2b_Wih};
    const float* bias_src[4] = {l1f_b,   l1b_b,   l2f_b,   l2b_b};
    for (int d = 0; d < 4; d++){
        cvtpad_inter<<<(Gn*EnP + 255)/256, 256, 0, stream>>>(wih_src[d], WihI + (long)d*655360);
        bias_inter<<<8, 256, 0, stream>>>(bias_src[d], biasI + d*2048);
    }
    cvtpad_kernel<<<(1024*2048 + 255)/256, 256, 0, stream>>>(fc1_w, fc1wb, 1024, 2048, 2048);
    convw3_kernel<<<(128*3072 + 255)/256, 256, 0, stream>>>(conv_w, cw3);

    // persistent biLSTM layers (64 co-resident blocks each)
    dim3 gl(32, 2);
    lstm_persist<<<gl, 256, 0, stream>>>(l1f_Whh, l1b_Whh, WihI, 655360L, biasI,
        featp, rmF1t, rmB1t, h1A, h1B, c1, vbuf, lenf, Sn, Sn, sync);
    lstm_persist<<<gl, 256, 0, stream>>>(l2f_Whh, l2b_Whh, WihI + 2L*655360, 655360L, biasI + 4096,
        aspp, rm2Ft, rm2Bt, h2A, h2B, c2, ebuf, lena, Tn, Tn, sync + 32);

    // F2 = e @ W1^T  (fc1_w cols 0..1023)
    dim3 gF(C2n/128, (Bn*Tn)/128);  // (8, 8)
    mfma_gemm<<<gF, 256, 0, stream>>>(ebuf, C2n, nullptr, fc1wb, 2048, nullptr, F2b, C2n, Bn*Tn, C2n, C2n);

    // 2 CPT iterations: mo = v @ W2^T, then fused attention/fc1/residual
    dim3 gm(C2n/128, (Bn*Sn)/128);  // (8, 128)
    for (int it = 0; it < 2; it++){
        mfma_gemm<<<gm, 256, 0, stream>>>(vbuf, C2n, nullptr, fc1wb + 1024, 2048, nullptr, mo, C2n, Bn*Sn, C2n, C2n);
        attn2_kernel<<<dim3(Sn, Bn), 256, 0, stream>>>(vbuf, ebuf, F2b, mo, fc1_b, wpos);
    }

    conv_mm<<<Bn, 256, 0, stream>>>(vbuf, cw3, zrow, conv_b, zmax);
    loss_kernel<<<1, 128, 0, stream>>>(zmax, fc_w, fc_b, label, (float*)d_out);
}